// Round 13
// baseline (115.815 us; speedup 1.0000x reference)
//
#include <hip/hip_runtime.h>
#include <hip/hip_fp16.h>
#include <math.h>

#define V_ 3
#define B_ 2
#define C_ 32
#define D_ 32
#define H_ 128
#define W_ 160
#define HW_ (H_*W_)
#define NPIX_ (B_*H_*W_)              // 40960
#define NCOST_ (B_*D_*H_*W_)          // 1310720

struct H8 { __half2 h[4]; };          // 8 fp16 channels (16B)

// ---------------- 4x4 double inverse (adjugate) ----------------
__device__ __forceinline__ void inv4(const double* m, double* o) {
    double inv[16];
    inv[0]  =  m[5]*m[10]*m[15] - m[5]*m[11]*m[14] - m[9]*m[6]*m[15] + m[9]*m[7]*m[14] + m[13]*m[6]*m[11] - m[13]*m[7]*m[10];
    inv[4]  = -m[4]*m[10]*m[15] + m[4]*m[11]*m[14] + m[8]*m[6]*m[15] - m[8]*m[7]*m[14] - m[12]*m[6]*m[11] + m[12]*m[7]*m[10];
    inv[8]  =  m[4]*m[9]*m[15]  - m[4]*m[11]*m[13] - m[8]*m[5]*m[15] + m[8]*m[7]*m[13] + m[12]*m[5]*m[11] - m[12]*m[7]*m[9];
    inv[12] = -m[4]*m[9]*m[14]  + m[4]*m[10]*m[13] + m[8]*m[5]*m[14] - m[8]*m[6]*m[13] - m[12]*m[5]*m[10] + m[12]*m[6]*m[9];
    inv[1]  = -m[1]*m[10]*m[15] + m[1]*m[11]*m[14] + m[9]*m[2]*m[15] - m[9]*m[3]*m[14] - m[13]*m[2]*m[11] + m[13]*m[3]*m[10];
    inv[5]  =  m[0]*m[10]*m[15] - m[0]*m[11]*m[14] - m[8]*m[2]*m[15] + m[8]*m[3]*m[14] + m[12]*m[2]*m[11] - m[12]*m[3]*m[10];
    inv[9]  = -m[0]*m[9]*m[15]  + m[0]*m[11]*m[13] + m[8]*m[1]*m[15] - m[8]*m[3]*m[13] - m[12]*m[1]*m[11] + m[12]*m[3]*m[9];
    inv[13] =  m[0]*m[9]*m[14]  - m[0]*m[10]*m[13] - m[8]*m[1]*m[14] + m[8]*m[2]*m[13] + m[12]*m[1]*m[10] - m[12]*m[2]*m[9];
    inv[2]  =  m[1]*m[6]*m[15]  - m[1]*m[7]*m[14]  - m[5]*m[2]*m[15] + m[5]*m[3]*m[14] + m[13]*m[2]*m[7]  - m[13]*m[3]*m[6];
    inv[6]  = -m[0]*m[6]*m[15]  + m[0]*m[7]*m[14]  + m[4]*m[2]*m[15] - m[4]*m[3]*m[14] - m[12]*m[2]*m[7]  + m[12]*m[3]*m[6];
    inv[10] =  m[0]*m[5]*m[15]  - m[0]*m[7]*m[13]  - m[4]*m[1]*m[15] + m[4]*m[3]*m[13] + m[12]*m[1]*m[7]  - m[12]*m[3]*m[5];
    inv[14] = -m[0]*m[5]*m[14]  + m[0]*m[6]*m[13]  + m[4]*m[1]*m[14] - m[4]*m[2]*m[13] - m[12]*m[1]*m[6]  + m[12]*m[2]*m[5];
    inv[3]  = -m[1]*m[6]*m[11]  + m[1]*m[7]*m[10]  + m[5]*m[2]*m[11] - m[5]*m[3]*m[10] - m[9]*m[2]*m[7]   + m[9]*m[3]*m[6];
    inv[7]  =  m[0]*m[6]*m[11]  - m[0]*m[7]*m[10]  - m[4]*m[2]*m[11] + m[4]*m[3]*m[10] + m[8]*m[2]*m[7]   - m[8]*m[3]*m[6];
    inv[11] = -m[0]*m[5]*m[11]  + m[0]*m[7]*m[9]   + m[4]*m[1]*m[11] - m[4]*m[3]*m[9]  - m[8]*m[1]*m[7]   + m[8]*m[3]*m[5];
    inv[15] =  m[0]*m[5]*m[10]  - m[0]*m[6]*m[9]   - m[4]*m[1]*m[10] + m[4]*m[2]*m[9]  + m[8]*m[1]*m[6]   - m[8]*m[2]*m[5];
    double det = m[0]*inv[0] + m[1]*inv[4] + m[2]*inv[8] + m[3]*inv[12];
    det = 1.0 / det;
    for (int i = 0; i < 16; i++) o[i] = inv[i] * det;
}

__device__ __forceinline__ void mm4(const double* A, const double* Bm, double* Cm) {
    for (int r = 0; r < 4; r++)
        for (int c = 0; c < 4; c++) {
            double s = 0.0;
            for (int k = 0; k < 4; k++) s += A[r*4+k] * Bm[k*4+c];
            Cm[r*4+c] = s;
        }
}

__global__ void proj_kernel(const float* __restrict__ K, const float* __restrict__ c2w,
                            float* __restrict__ proj_out) {
    int t = blockIdx.x * blockDim.x + threadIdx.x;
    if (t >= (V_-1) * B_) return;
    int vv = t / B_;
    int b  = t % B_;
    int v  = vv + 1;
    double sc[16], rc[16];
    for (int i = 0; i < 16; i++) {
        sc[i] = (double)c2w[((size_t)v * B_ + b) * 16 + i];
        rc[i] = (double)c2w[((size_t)0 * B_ + b) * 16 + i];
    }
    double sw[16], rw[16];
    inv4(sc, sw);
    inv4(rc, rw);
    double sK[16], rK[16];
    for (int i = 0; i < 16; i++) { sK[i] = sw[i]; rK[i] = rw[i]; }
    for (int r = 0; r < 3; r++)
        for (int c = 0; c < 3; c++) {
            sK[r*4+c] = (double)K[((size_t)v * B_ + b) * 9 + r*3 + c];
            rK[r*4+c] = (double)K[((size_t)0 * B_ + b) * 9 + r*3 + c];
        }
    double sp[16], rp[16], rpi[16], P[16];
    mm4(sK, sw, sp);
    mm4(rK, rw, rp);
    inv4(rp, rpi);
    mm4(sp, rpi, P);
    float* o = proj_out + (size_t)t * 12;
    for (int r = 0; r < 3; r++)
        for (int c = 0; c < 3; c++) o[r*3+c] = (float)P[r*4+c];
    for (int r = 0; r < 3; r++) o[9+r] = (float)P[r*4+3];
}

// features (V,B,C,H,W) -> refT f32 (B,H,W,C) for view 0, fh fp16 (2,B,H,W,C)
__global__ void __launch_bounds__(256) transpose_kernel(const float* __restrict__ feat,
                                                        float* __restrict__ refT,
                                                        __half* __restrict__ fh) {
    __shared__ float lds[32][33];
    int bid = blockIdx.x;
    int xt = bid % (W_ / 32);
    int y  = (bid / (W_ / 32)) % H_;
    int vb = bid / ((W_ / 32) * H_);
    int v = vb >> 1, b = vb & 1;
    int x0 = xt * 32;
    int tid = threadIdx.x;
    int xl = tid & 31;
    int ch = tid >> 5;
#pragma unroll
    for (int it = 0; it < 4; it++) {
        int c = it * 8 + ch;
        lds[c][xl] = feat[((size_t)(vb * C_ + c) * H_ + y) * W_ + x0 + xl];
    }
    __syncthreads();
    int c4 = tid & 7;
    int xw = tid >> 3;
    float4 o;
    o.x = lds[c4*4+0][xw];
    o.y = lds[c4*4+1][xw];
    o.z = lds[c4*4+2][xw];
    o.w = lds[c4*4+3][xw];
    size_t pix = (size_t)(b * H_ + y) * W_ + x0 + xw;
    if (v == 0) {
        *(float4*)(refT + pix * C_ + c4 * 4) = o;
    } else {
        uint2 st;
        __half2 p0 = __floats2half2_rn(o.x, o.y);
        __half2 p1 = __floats2half2_rn(o.z, o.w);
        st.x = *(unsigned int*)&p0;
        st.y = *(unsigned int*)&p1;
        size_t dst = ((size_t)((v - 1) * B_ + b) * HW_ + (y * W_ + x0 + xw));
        *(uint2*)((unsigned short*)fh + dst * C_ + c4 * 4) = st;
    }
}

// cost (B,D,H,W): block = 32 consecutive pixels x 8 depths (unchanged from R8).
__global__ void __launch_bounds__(256, 4) cost_kernel(const float* __restrict__ refT,
                                                      const __half* __restrict__ fh,
                                                      const float* __restrict__ depth,
                                                      const float* __restrict__ unc,
                                                      const float* __restrict__ proj,
                                                      float* __restrict__ cost) {
    __shared__ float4 lw[2][256];
    __shared__ int4   lo[2][256];
    int tid = threadIdx.x;
    const int blocksPerDt = NPIX_ / 32;           // 1280; grid = 5120
    int dt      = blockIdx.x / blocksPerDt;       // 0..3
    int pixbase = (blockIdx.x % blocksPerDt) * 32;
    int d0 = dt * 8;

    // ---- phase 1: projection per (pixel, d) ----
    {
        int pixl = tid & 31;
        int dl   = tid >> 5;
        int pix = pixbase + pixl;
        int x = pix % W_;
        int y = (pix / W_) % H_;
        int b = pix / HW_;
        float dep = depth[((b * D_ + d0 + dl) * H_ + y) * W_ + x];
        float fx = (float)x, fy = (float)y;
#pragma unroll
        for (int v = 0; v < 2; v++) {
            const float* P = proj + ((size_t)v * B_ + b) * 12;
            float rx = P[0]*fx + P[1]*fy + P[2];
            float ry = P[3]*fx + P[4]*fy + P[5];
            float rz = P[6]*fx + P[7]*fy + P[8];
            float px = rx * dep + P[9];
            float py = ry * dep + P[10];
            float pz = rz * dep + P[11];
            float inv_pz = 1.0f / pz;
            float t0 = px * inv_pz;
            float t1 = py * inv_pz;
            float gx = t0 / ((W_ - 1) * 0.5f) - 1.0f;
            float gy = t1 / ((H_ - 1) * 0.5f) - 1.0f;
            float ix = ((gx + 1.0f) * W_ - 1.0f) * 0.5f;
            float iy = ((gy + 1.0f) * H_ - 1.0f) * 0.5f;
            float x0f = floorf(ix), y0f = floorf(iy);
            float wx = ix - x0f, wy = iy - y0f;
            int x0 = (int)x0f, y0 = (int)y0f;
            int x1 = x0 + 1, y1 = y0 + 1;
            bool vx0 = (x0 >= 0) && (x0 <= W_ - 1);
            bool vx1 = (x1 >= 0) && (x1 <= W_ - 1);
            bool vy0 = (y0 >= 0) && (y0 <= H_ - 1);
            bool vy1 = (y1 >= 0) && (y1 <= H_ - 1);
            float4 w;
            w.x = (vx0 && vy0) ? (1.0f - wx) * (1.0f - wy) : 0.0f;
            w.y = (vx1 && vy0) ? wx * (1.0f - wy) : 0.0f;
            w.z = (vx0 && vy1) ? (1.0f - wx) * wy : 0.0f;
            w.w = (vx1 && vy1) ? wx * wy : 0.0f;
            int xc0 = min(max(x0, 0), W_ - 1), xc1 = min(max(x1, 0), W_ - 1);
            int yc0 = min(max(y0, 0), H_ - 1), yc1 = min(max(y1, 0), H_ - 1);
            int4 o;
            o.x = yc0 * W_ + xc0;
            o.y = yc0 * W_ + xc1;
            o.z = yc1 * W_ + xc0;
            o.w = yc1 * W_ + xc1;
            lw[v][tid] = w;
            lo[v][tid] = o;
        }
    }
    __syncthreads();

    // ---- phase 2: fp16 gathers, 4 lanes per pixel ----
    int c8 = tid & 3;
    int g  = (tid >> 2) & 31;
    int h  = tid >> 7;
    int pix = pixbase + g;
    int x = pix % W_;
    int y = (pix / W_) % H_;
    int b = pix / HW_;

    const float4* rT4 = (const float4*)refT;
    const float4 r0 = rT4[(size_t)pix * 8 + c8 * 2];
    const float4 r1 = rT4[(size_t)pix * 8 + c8 * 2 + 1];
    const H8* fh8 = (const H8*)fh;
    size_t baseA = ((size_t)(0 * B_ + b) * HW_) * 4 + c8;
    size_t baseB = ((size_t)(1 * B_ + b) * HW_) * 4 + c8;

    float u = unc[pix];
    float sig = 1.0f / (1.0f + __expf(-u));

    float myres = 0.0f;
#pragma unroll
    for (int i = 0; i < 4; i++) {
        int e = (h * 4 + i) * 32 + g;
        float pv[2];
#pragma unroll
        for (int v = 0; v < 2; v++) {
            float4 Wt = lw[v][e];
            int4   Of = lo[v][e];
            size_t base = v ? baseB : baseA;
            H8 a  = fh8[base + (size_t)Of.x * 4];
            H8 bq = fh8[base + (size_t)Of.y * 4];
            H8 cq = fh8[base + (size_t)Of.z * 4];
            H8 eq = fh8[base + (size_t)Of.w * 4];
            __half2 w0 = __float2half2_rn(Wt.x);
            __half2 w1 = __float2half2_rn(Wt.y);
            __half2 w2 = __float2half2_rn(Wt.z);
            __half2 w3 = __float2half2_rn(Wt.w);
            __half2 acc0 = __hmul2(w0, a.h[0]);
            __half2 acc1 = __hmul2(w0, a.h[1]);
            __half2 acc2 = __hmul2(w0, a.h[2]);
            __half2 acc3 = __hmul2(w0, a.h[3]);
            acc0 = __hfma2(w1, bq.h[0], acc0);
            acc1 = __hfma2(w1, bq.h[1], acc1);
            acc2 = __hfma2(w1, bq.h[2], acc2);
            acc3 = __hfma2(w1, bq.h[3], acc3);
            acc0 = __hfma2(w2, cq.h[0], acc0);
            acc1 = __hfma2(w2, cq.h[1], acc1);
            acc2 = __hfma2(w2, cq.h[2], acc2);
            acc3 = __hfma2(w2, cq.h[3], acc3);
            acc0 = __hfma2(w3, eq.h[0], acc0);
            acc1 = __hfma2(w3, eq.h[1], acc1);
            acc2 = __hfma2(w3, eq.h[2], acc2);
            acc3 = __hfma2(w3, eq.h[3], acc3);
            float2 f0 = __half22float2(acc0);
            float2 f1 = __half22float2(acc1);
            float2 f2 = __half22float2(acc2);
            float2 f3 = __half22float2(acc3);
            float p = r0.x*f0.x + r0.y*f0.y + r0.z*f1.x + r0.w*f1.y
                    + r1.x*f2.x + r1.y*f2.y + r1.z*f3.x + r1.w*f3.y;
            p += __shfl_xor(p, 1);
            p += __shfl_xor(p, 2);
            pv[v] = p;
        }
        float r = fminf(pv[0], pv[1]) * sig;
        if (c8 == i) myres = r;
    }
    cost[((b * D_ + d0 + h * 4 + c8) * H_ + y) * W_ + x] = myres;
}

// w_feat: block = 32 pixels; 5x36 neighborhood staged in LDS (zero-padded,
// so OOB dots are naturally 0); 8 lanes per pixel; softmax over 25 dots.
__global__ void __launch_bounds__(256) wfeat_kernel(const float* __restrict__ refT,
                                                    float* __restrict__ wfeat) {
    __shared__ float4 wbox[5 * 36 * 8];   // 23 KB
    int tid = threadIdx.x;
    int g  = tid >> 3;
    int c4 = tid & 7;
    int pixbase = blockIdx.x * 32;
    int x0 = pixbase % W_;
    int yb = (pixbase / W_) % H_;
    int b  = pixbase / HW_;
    const float4* rT4 = (const float4*)refT;

    for (int e = tid; e < 5 * 36 * 8; e += 256) {
        int ent = e >> 3, q = e & 7;
        int ry = ent / 36, rx = ent - ry * 36;
        int yy = yb + ry - 2, xx = x0 + rx - 2;
        float4 val = make_float4(0.f, 0.f, 0.f, 0.f);
        if (yy >= 0 && yy < H_ && xx >= 0 && xx < W_)
            val = rT4[(size_t)((b * H_ + yy) * W_ + xx) * 8 + q];
        wbox[e] = val;
    }
    __syncthreads();

    const float4 r = wbox[(2 * 36 + g + 2) * 8 + c4];
    float logit[25];
#pragma unroll
    for (int k = 0; k < 25; k++) {
        int dy = k / 5, dx = k % 5;
        float4 q = wbox[(dy * 36 + g + dx) * 8 + c4];
        float p = r.x*q.x + r.y*q.y + r.z*q.z + r.w*q.w;
        p += __shfl_xor(p, 1);
        p += __shfl_xor(p, 2);
        p += __shfl_xor(p, 4);
        logit[k] = p;
    }
    float m = logit[0];
#pragma unroll
    for (int k = 1; k < 25; k++) m = fmaxf(m, logit[k]);
    float s = 0.0f;
#pragma unroll
    for (int k = 0; k < 25; k++) { logit[k] = __expf(logit[k] - m); s += logit[k]; }
    float inv_s = 1.0f / s;
    int pix = pixbase + g;
#pragma unroll
    for (int t = 0; t < 3; t++) {
        int k = c4 + 8 * t;
        wfeat[(size_t)k * NPIX_ + pix] = logit[k] * inv_s;
    }
    if (c4 == 0) wfeat[(size_t)24 * NPIX_ + pix] = logit[24] * inv_s;
}

// agg: block = 8x x 4y pixel tile x 16-depth slab. LDS ~16.3 KB -> high occupancy.
// dtile/ctile layout [pixidx=ry*12+rx][17]: bank = (17*pixidx + d) mod 32 is a
// bijection in pixidx (17 odd) -> conflict-free taps and stores.
#define TX_ 8
#define TY_ 4
#define DSLAB 16
#define DT(arr, dd, ry, rx) arr[(((ry) * 12 + (rx)) * (DSLAB + 1)) + (dd)]
__global__ void __launch_bounds__(256, 6) agg_kernel(const float* __restrict__ depth,
                                                     const float* __restrict__ cost,
                                                     const float* __restrict__ wfeat,
                                                     float* __restrict__ agg) {
    __shared__ float dtile[96 * (DSLAB + 1)];   // 6.5 KB
    __shared__ float ctile[96 * (DSLAB + 1)];   // 6.5 KB
    __shared__ float wf[25][32];                // 3.2 KB
    int tid = threadIdx.x;
    int bid = blockIdx.x;
    int slab = bid & 1;                         // d-slab minor: halo shared in L2
    int tile = bid >> 1;
    const int XT = W_ / TX_;                    // 20
    int xt = tile % XT;
    int yt = (tile / XT) % (H_ / TY_);
    int b  = tile / (XT * (H_ / TY_));
    int x0 = xt * TX_;
    int yb = yt * TY_;
    int d0 = slab * DSLAB;

    // stage wf (25 x 32 pixels of this tile)
    for (int li = tid; li < 25 * 32; li += 256) {
        int k  = li >> 5;
        int pp = li & 31;
        int px = pp & 7, py = pp >> 3;
        wf[k][pp] = wfeat[(size_t)k * NPIX_ + (b * H_ + yb + py) * W_ + x0 + px];
    }
    // stage depth + cost slab: 16 d x 8 ry x 12 rx
    for (int li = tid; li < DSLAB * 96; li += 256) {
        int dd  = li / 96;
        int rem = li - dd * 96;
        int ry  = rem / 12;
        int rx  = rem - ry * 12;
        int yy = yb + ry - 2;
        int xx = x0 + rx - 2;
        bool ok = (yy >= 0) && (yy < H_) && (xx >= 0) && (xx < W_);
        size_t gidx = ((size_t)(b * D_ + d0 + dd) * H_ + yy) * W_ + xx;
        DT(dtile, dd, ry, rx) = ok ? depth[gidx] : 0.0f;
        DT(ctile, dd, ry, rx) = ok ? cost[gidx]  : 0.0f;
    }
    __syncthreads();

    int p    = tid & 31;
    int px = p & 7, py = p >> 3;
    int dgrp = tid >> 5;   // 0..7, each handles 2 depths
#pragma unroll
    for (int i = 0; i < 2; i++) {
        int dd = dgrp * 2 + i;
        float dc = DT(dtile, dd, py + 2, px + 2);

        float wd[25];
        float m1 = -1e30f;
#pragma unroll
        for (int k = 0; k < 25; k++) {
            int dy = k / 5, dx = k % 5;
            float nd = DT(dtile, dd, py + dy, px + dx);
            float l = -fabsf(nd - dc);
            wd[k] = l;
            m1 = fmaxf(m1, l);
        }
        float s1 = 0.0f;
#pragma unroll
        for (int k = 0; k < 25; k++) { wd[k] = __expf(wd[k] - m1); s1 += wd[k]; }
        float inv_s1 = 1.0f / s1;

        float lg[25];
        float m2 = -1e30f;
#pragma unroll
        for (int k = 0; k < 25; k++) {
            float l = (wd[k] * inv_s1) * wf[k][p];
            lg[k] = l;
            m2 = fmaxf(m2, l);
        }
        float s2 = 0.0f;
        float acc = 0.0f;
#pragma unroll
        for (int k = 0; k < 25; k++) {
            float e = __expf(lg[k] - m2);
            s2 += e;
            int dy = k / 5, dx = k % 5;
            acc += DT(ctile, dd, py + dy, px + dx) * e;
        }
        agg[((size_t)(b * D_ + d0 + dd) * H_ + yb + py) * W_ + x0 + px] = acc / s2;
    }
}

// final: per-pixel softmax over D + expectation
__global__ void __launch_bounds__(256) final_kernel(const float* __restrict__ agg,
                                                    const float* __restrict__ depth,
                                                    float* __restrict__ out) {
    int idx = blockIdx.x * 256 + threadIdx.x;
    if (idx >= NPIX_) return;
    int x = idx % W_;
    int y = (idx / W_) % H_;
    int b = idx / (W_ * H_);
    size_t base = ((size_t)(b * D_) * H_ + y) * W_ + x;
    float a[D_];
    float m = -1e30f;
#pragma unroll
    for (int d = 0; d < D_; d++) {
        a[d] = agg[base + (size_t)d * HW_];
        m = fmaxf(m, a[d]);
    }
    float s = 0.0f, ws = 0.0f;
#pragma unroll
    for (int d = 0; d < D_; d++) {
        float e = __expf(a[d] - m);
        s += e;
        ws += e * depth[base + (size_t)d * HW_];
    }
    out[idx] = ws / s;
}

extern "C" void kernel_launch(void* const* d_in, const int* in_sizes, int n_in,
                              void* d_out, int out_size, void* d_ws, size_t ws_size,
                              hipStream_t stream) {
    const float* features = (const float*)d_in[0];  // (3,2,32,128,160)
    const float* intr     = (const float*)d_in[1];  // (3,2,3,3)
    const float* c2w      = (const float*)d_in[2];  // (3,2,4,4)
    const float* depth    = (const float*)d_in[3];  // (2,32,128,160)
    const float* unc      = (const float*)d_in[4];  // (2,128,160)
    float* out = (float*)d_out;

    float*  ws    = (float*)d_ws;
    float*  refT  = ws;                                         // B*HW*C f32
    __half* fh    = (__half*)(refT + (size_t)B_ * HW_ * C_);    // 2*B*HW*C fp16
    float*  cost  = (float*)(fh + (size_t)2 * B_ * HW_ * C_);   // NCOST_
    float*  wfeat = cost + NCOST_;                              // 25*NPIX_
    float*  agg   = wfeat + (size_t)25 * NPIX_;                 // NCOST_
    float*  proj  = agg + NCOST_;                               // 48

    hipLaunchKernelGGL(proj_kernel, dim3(1), dim3(64), 0, stream, intr, c2w, proj);
    hipLaunchKernelGGL(transpose_kernel, dim3(V_ * B_ * H_ * (W_ / 32)), dim3(256), 0, stream,
                       features, refT, fh);
    hipLaunchKernelGGL(cost_kernel, dim3((NPIX_ * 4) / 32), dim3(256), 0, stream,
                       refT, fh, depth, unc, proj, cost);
    hipLaunchKernelGGL(wfeat_kernel, dim3(NPIX_ / 32), dim3(256), 0, stream, refT, wfeat);
    hipLaunchKernelGGL(agg_kernel, dim3((NPIX_ / (TX_ * TY_)) * (D_ / DSLAB)), dim3(256), 0, stream,
                       depth, cost, wfeat, agg);
    hipLaunchKernelGGL(final_kernel, dim3(NPIX_ / 256), dim3(256), 0, stream, agg, depth, out);
}

// Round 14
// 98.784 us; speedup vs baseline: 1.1724x; 1.1724x over previous
//
#include <hip/hip_runtime.h>
#include <hip/hip_fp16.h>
#include <math.h>

#define V_ 3
#define B_ 2
#define C_ 32
#define D_ 32
#define H_ 128
#define W_ 160
#define HW_ (H_*W_)
#define NPIX_ (B_*H_*W_)              // 40960
#define NCOST_ (B_*D_*H_*W_)          // 1310720

struct H8 { __half2 h[4]; };          // 8 fp16 channels (16B)

// ---------------- 4x4 double inverse (adjugate) ----------------
__device__ __forceinline__ void inv4(const double* m, double* o) {
    double inv[16];
    inv[0]  =  m[5]*m[10]*m[15] - m[5]*m[11]*m[14] - m[9]*m[6]*m[15] + m[9]*m[7]*m[14] + m[13]*m[6]*m[11] - m[13]*m[7]*m[10];
    inv[4]  = -m[4]*m[10]*m[15] + m[4]*m[11]*m[14] + m[8]*m[6]*m[15] - m[8]*m[7]*m[14] - m[12]*m[6]*m[11] + m[12]*m[7]*m[10];
    inv[8]  =  m[4]*m[9]*m[15]  - m[4]*m[11]*m[13] - m[8]*m[5]*m[15] + m[8]*m[7]*m[13] + m[12]*m[5]*m[11] - m[12]*m[7]*m[9];
    inv[12] = -m[4]*m[9]*m[14]  + m[4]*m[10]*m[13] + m[8]*m[5]*m[14] - m[8]*m[6]*m[13] - m[12]*m[5]*m[10] + m[12]*m[6]*m[9];
    inv[1]  = -m[1]*m[10]*m[15] + m[1]*m[11]*m[14] + m[9]*m[2]*m[15] - m[9]*m[3]*m[14] - m[13]*m[2]*m[11] + m[13]*m[3]*m[10];
    inv[5]  =  m[0]*m[10]*m[15] - m[0]*m[11]*m[14] - m[8]*m[2]*m[15] + m[8]*m[3]*m[14] + m[12]*m[2]*m[11] - m[12]*m[3]*m[10];
    inv[9]  = -m[0]*m[9]*m[15]  + m[0]*m[11]*m[13] + m[8]*m[1]*m[15] - m[8]*m[3]*m[13] - m[12]*m[1]*m[11] + m[12]*m[3]*m[9];
    inv[13] =  m[0]*m[9]*m[14]  - m[0]*m[10]*m[13] - m[8]*m[1]*m[14] + m[8]*m[2]*m[13] + m[12]*m[1]*m[10] - m[12]*m[2]*m[9];
    inv[2]  =  m[1]*m[6]*m[15]  - m[1]*m[7]*m[14]  - m[5]*m[2]*m[15] + m[5]*m[3]*m[14] + m[13]*m[2]*m[7]  - m[13]*m[3]*m[6];
    inv[6]  = -m[0]*m[6]*m[15]  + m[0]*m[7]*m[14]  + m[4]*m[2]*m[15] - m[4]*m[3]*m[14] - m[12]*m[2]*m[7]  + m[12]*m[3]*m[6];
    inv[10] =  m[0]*m[5]*m[15]  - m[0]*m[7]*m[13]  - m[4]*m[1]*m[15] + m[4]*m[3]*m[13] + m[12]*m[1]*m[7]  - m[12]*m[3]*m[5];
    inv[14] = -m[0]*m[5]*m[14]  + m[0]*m[6]*m[13]  + m[4]*m[1]*m[14] - m[4]*m[2]*m[13] - m[12]*m[1]*m[6]  + m[12]*m[2]*m[5];
    inv[3]  = -m[1]*m[6]*m[11]  + m[1]*m[7]*m[10]  + m[5]*m[2]*m[11] - m[5]*m[3]*m[10] - m[9]*m[2]*m[7]   + m[9]*m[3]*m[6];
    inv[7]  =  m[0]*m[6]*m[11]  - m[0]*m[7]*m[10]  - m[4]*m[2]*m[11] + m[4]*m[3]*m[10] + m[8]*m[2]*m[7]   - m[8]*m[3]*m[6];
    inv[11] = -m[0]*m[5]*m[11]  + m[0]*m[7]*m[9]   + m[4]*m[1]*m[11] - m[4]*m[3]*m[9]  - m[8]*m[1]*m[7]   + m[8]*m[3]*m[5];
    inv[15] =  m[0]*m[5]*m[10]  - m[0]*m[6]*m[9]   - m[4]*m[1]*m[10] + m[4]*m[2]*m[9]  + m[8]*m[1]*m[6]   - m[8]*m[2]*m[5];
    double det = m[0]*inv[0] + m[1]*inv[4] + m[2]*inv[8] + m[3]*inv[12];
    det = 1.0 / det;
    for (int i = 0; i < 16; i++) o[i] = inv[i] * det;
}

__device__ __forceinline__ void mm4(const double* A, const double* Bm, double* Cm) {
    for (int r = 0; r < 4; r++)
        for (int c = 0; c < 4; c++) {
            double s = 0.0;
            for (int k = 0; k < 4; k++) s += A[r*4+k] * Bm[k*4+c];
            Cm[r*4+c] = s;
        }
}

__global__ void proj_kernel(const float* __restrict__ K, const float* __restrict__ c2w,
                            float* __restrict__ proj_out) {
    int t = blockIdx.x * blockDim.x + threadIdx.x;
    if (t >= (V_-1) * B_) return;
    int vv = t / B_;
    int b  = t % B_;
    int v  = vv + 1;
    double sc[16], rc[16];
    for (int i = 0; i < 16; i++) {
        sc[i] = (double)c2w[((size_t)v * B_ + b) * 16 + i];
        rc[i] = (double)c2w[((size_t)0 * B_ + b) * 16 + i];
    }
    double sw[16], rw[16];
    inv4(sc, sw);
    inv4(rc, rw);
    double sK[16], rK[16];
    for (int i = 0; i < 16; i++) { sK[i] = sw[i]; rK[i] = rw[i]; }
    for (int r = 0; r < 3; r++)
        for (int c = 0; c < 3; c++) {
            sK[r*4+c] = (double)K[((size_t)v * B_ + b) * 9 + r*3 + c];
            rK[r*4+c] = (double)K[((size_t)0 * B_ + b) * 9 + r*3 + c];
        }
    double sp[16], rp[16], rpi[16], P[16];
    mm4(sK, sw, sp);
    mm4(rK, rw, rp);
    inv4(rp, rpi);
    mm4(sp, rpi, P);
    float* o = proj_out + (size_t)t * 12;
    for (int r = 0; r < 3; r++)
        for (int c = 0; c < 3; c++) o[r*3+c] = (float)P[r*4+c];
    for (int r = 0; r < 3; r++) o[9+r] = (float)P[r*4+3];
}

// features (V,B,C,H,W) -> refT f32 (B,H,W,C) for view 0, fh fp16 (2,B,H,W,C)
__global__ void __launch_bounds__(256) transpose_kernel(const float* __restrict__ feat,
                                                        float* __restrict__ refT,
                                                        __half* __restrict__ fh) {
    __shared__ float lds[32][33];
    int bid = blockIdx.x;
    int xt = bid % (W_ / 32);
    int y  = (bid / (W_ / 32)) % H_;
    int vb = bid / ((W_ / 32) * H_);
    int v = vb >> 1, b = vb & 1;
    int x0 = xt * 32;
    int tid = threadIdx.x;
    int xl = tid & 31;
    int ch = tid >> 5;
#pragma unroll
    for (int it = 0; it < 4; it++) {
        int c = it * 8 + ch;
        lds[c][xl] = feat[((size_t)(vb * C_ + c) * H_ + y) * W_ + x0 + xl];
    }
    __syncthreads();
    int c4 = tid & 7;
    int xw = tid >> 3;
    float4 o;
    o.x = lds[c4*4+0][xw];
    o.y = lds[c4*4+1][xw];
    o.z = lds[c4*4+2][xw];
    o.w = lds[c4*4+3][xw];
    size_t pix = (size_t)(b * H_ + y) * W_ + x0 + xw;
    if (v == 0) {
        *(float4*)(refT + pix * C_ + c4 * 4) = o;
    } else {
        uint2 st;
        __half2 p0 = __floats2half2_rn(o.x, o.y);
        __half2 p1 = __floats2half2_rn(o.z, o.w);
        st.x = *(unsigned int*)&p0;
        st.y = *(unsigned int*)&p1;
        size_t dst = ((size_t)((v - 1) * B_ + b) * HW_ + (y * W_ + x0 + xw));
        *(uint2*)((unsigned short*)fh + dst * C_ + c4 * 4) = st;
    }
}

// cost (B,D,H,W): block = 32 consecutive pixels x 8 depths (unchanged from R8).
__global__ void __launch_bounds__(256, 4) cost_kernel(const float* __restrict__ refT,
                                                      const __half* __restrict__ fh,
                                                      const float* __restrict__ depth,
                                                      const float* __restrict__ unc,
                                                      const float* __restrict__ proj,
                                                      float* __restrict__ cost) {
    __shared__ float4 lw[2][256];
    __shared__ int4   lo[2][256];
    int tid = threadIdx.x;
    const int blocksPerDt = NPIX_ / 32;           // 1280; grid = 5120
    int dt      = blockIdx.x / blocksPerDt;       // 0..3
    int pixbase = (blockIdx.x % blocksPerDt) * 32;
    int d0 = dt * 8;

    // ---- phase 1: projection per (pixel, d) ----
    {
        int pixl = tid & 31;
        int dl   = tid >> 5;
        int pix = pixbase + pixl;
        int x = pix % W_;
        int y = (pix / W_) % H_;
        int b = pix / HW_;
        float dep = depth[((b * D_ + d0 + dl) * H_ + y) * W_ + x];
        float fx = (float)x, fy = (float)y;
#pragma unroll
        for (int v = 0; v < 2; v++) {
            const float* P = proj + ((size_t)v * B_ + b) * 12;
            float rx = P[0]*fx + P[1]*fy + P[2];
            float ry = P[3]*fx + P[4]*fy + P[5];
            float rz = P[6]*fx + P[7]*fy + P[8];
            float px = rx * dep + P[9];
            float py = ry * dep + P[10];
            float pz = rz * dep + P[11];
            float inv_pz = 1.0f / pz;
            float t0 = px * inv_pz;
            float t1 = py * inv_pz;
            float gx = t0 / ((W_ - 1) * 0.5f) - 1.0f;
            float gy = t1 / ((H_ - 1) * 0.5f) - 1.0f;
            float ix = ((gx + 1.0f) * W_ - 1.0f) * 0.5f;
            float iy = ((gy + 1.0f) * H_ - 1.0f) * 0.5f;
            float x0f = floorf(ix), y0f = floorf(iy);
            float wx = ix - x0f, wy = iy - y0f;
            int x0 = (int)x0f, y0 = (int)y0f;
            int x1 = x0 + 1, y1 = y0 + 1;
            bool vx0 = (x0 >= 0) && (x0 <= W_ - 1);
            bool vx1 = (x1 >= 0) && (x1 <= W_ - 1);
            bool vy0 = (y0 >= 0) && (y0 <= H_ - 1);
            bool vy1 = (y1 >= 0) && (y1 <= H_ - 1);
            float4 w;
            w.x = (vx0 && vy0) ? (1.0f - wx) * (1.0f - wy) : 0.0f;
            w.y = (vx1 && vy0) ? wx * (1.0f - wy) : 0.0f;
            w.z = (vx0 && vy1) ? (1.0f - wx) * wy : 0.0f;
            w.w = (vx1 && vy1) ? wx * wy : 0.0f;
            int xc0 = min(max(x0, 0), W_ - 1), xc1 = min(max(x1, 0), W_ - 1);
            int yc0 = min(max(y0, 0), H_ - 1), yc1 = min(max(y1, 0), H_ - 1);
            int4 o;
            o.x = yc0 * W_ + xc0;
            o.y = yc0 * W_ + xc1;
            o.z = yc1 * W_ + xc0;
            o.w = yc1 * W_ + xc1;
            lw[v][tid] = w;
            lo[v][tid] = o;
        }
    }
    __syncthreads();

    // ---- phase 2: fp16 gathers, 4 lanes per pixel ----
    int c8 = tid & 3;
    int g  = (tid >> 2) & 31;
    int h  = tid >> 7;
    int pix = pixbase + g;
    int x = pix % W_;
    int y = (pix / W_) % H_;
    int b = pix / HW_;

    const float4* rT4 = (const float4*)refT;
    const float4 r0 = rT4[(size_t)pix * 8 + c8 * 2];
    const float4 r1 = rT4[(size_t)pix * 8 + c8 * 2 + 1];
    const H8* fh8 = (const H8*)fh;
    size_t baseA = ((size_t)(0 * B_ + b) * HW_) * 4 + c8;
    size_t baseB = ((size_t)(1 * B_ + b) * HW_) * 4 + c8;

    float u = unc[pix];
    float sig = 1.0f / (1.0f + __expf(-u));

    float myres = 0.0f;
#pragma unroll
    for (int i = 0; i < 4; i++) {
        int e = (h * 4 + i) * 32 + g;
        float pv[2];
#pragma unroll
        for (int v = 0; v < 2; v++) {
            float4 Wt = lw[v][e];
            int4   Of = lo[v][e];
            size_t base = v ? baseB : baseA;
            H8 a  = fh8[base + (size_t)Of.x * 4];
            H8 bq = fh8[base + (size_t)Of.y * 4];
            H8 cq = fh8[base + (size_t)Of.z * 4];
            H8 eq = fh8[base + (size_t)Of.w * 4];
            __half2 w0 = __float2half2_rn(Wt.x);
            __half2 w1 = __float2half2_rn(Wt.y);
            __half2 w2 = __float2half2_rn(Wt.z);
            __half2 w3 = __float2half2_rn(Wt.w);
            __half2 acc0 = __hmul2(w0, a.h[0]);
            __half2 acc1 = __hmul2(w0, a.h[1]);
            __half2 acc2 = __hmul2(w0, a.h[2]);
            __half2 acc3 = __hmul2(w0, a.h[3]);
            acc0 = __hfma2(w1, bq.h[0], acc0);
            acc1 = __hfma2(w1, bq.h[1], acc1);
            acc2 = __hfma2(w1, bq.h[2], acc2);
            acc3 = __hfma2(w1, bq.h[3], acc3);
            acc0 = __hfma2(w2, cq.h[0], acc0);
            acc1 = __hfma2(w2, cq.h[1], acc1);
            acc2 = __hfma2(w2, cq.h[2], acc2);
            acc3 = __hfma2(w2, cq.h[3], acc3);
            acc0 = __hfma2(w3, eq.h[0], acc0);
            acc1 = __hfma2(w3, eq.h[1], acc1);
            acc2 = __hfma2(w3, eq.h[2], acc2);
            acc3 = __hfma2(w3, eq.h[3], acc3);
            float2 f0 = __half22float2(acc0);
            float2 f1 = __half22float2(acc1);
            float2 f2 = __half22float2(acc2);
            float2 f3 = __half22float2(acc3);
            float p = r0.x*f0.x + r0.y*f0.y + r0.z*f1.x + r0.w*f1.y
                    + r1.x*f2.x + r1.y*f2.y + r1.z*f3.x + r1.w*f3.y;
            p += __shfl_xor(p, 1);
            p += __shfl_xor(p, 2);
            pv[v] = p;
        }
        float r = fminf(pv[0], pv[1]) * sig;
        if (c8 == i) myres = r;
    }
    cost[((b * D_ + d0 + h * 4 + c8) * H_ + y) * W_ + x] = myres;
}

// fused wfeat + agg + final (R10 structure, bank-clean LDS layouts):
// - wbox: float4 entries at stride 10 (2-way worst case on b128 reads)
// - dtile/ctile: pixel-major [pixidx=ry*12+rx][33] -> bank=(pixidx+d)%32,
//   conflict-free taps and stores (tap lanes' pixidx distinct mod 32)
// - wf: stride 33 -> conflict-free writes (bank=c4) and reads (bank=p)
#define TX_ 8
#define TY_ 4
#define AGP(arr, dd, ry, rx) arr[(((ry) * 12 + (rx)) * 33) + (dd)]
__global__ void __launch_bounds__(256) aggfinal_kernel(const float* __restrict__ refT,
                                                       const float* __restrict__ depth,
                                                       const float* __restrict__ cost,
                                                       float* __restrict__ out) {
    __shared__ float smem[2 * 96 * 33];       // 25.3 KB union: wbox (15.4) / dtile+ctile
    __shared__ float wf[25][33];
    __shared__ float aval[D_][32];
    int tid = threadIdx.x;
    int bid = blockIdx.x;
    const int XT = W_ / TX_;                  // 20
    int xt = bid % XT;
    int yt = (bid / XT) % (H_ / TY_);
    int b  = bid / (XT * (H_ / TY_));
    int x0 = xt * TX_;
    int yb = yt * TY_;

    // ---- phase A: wfeat (8 rows x 12 cols ref box, float4 stride 10) ----
    {
        float4* wbox = (float4*)smem;         // 96 entries * 10 stride * 16B = 15.4 KB
        const float4* rT4 = (const float4*)refT;
        for (int e = tid; e < 8 * 12 * 8; e += 256) {
            int ent = e >> 3, q = e & 7;
            int ry = ent / 12, rx = ent - ry * 12;
            int yy = yb + ry - 2, xx = x0 + rx - 2;
            float4 val = make_float4(0.f, 0.f, 0.f, 0.f);
            if (yy >= 0 && yy < H_ && xx >= 0 && xx < W_)
                val = rT4[(size_t)((b * H_ + yy) * W_ + xx) * 8 + q];
            wbox[ent * 10 + q] = val;
        }
        __syncthreads();

        int g  = tid >> 3;
        int c4 = tid & 7;
        int px = g & 7, py = g >> 3;
        const float4 r = wbox[((py + 2) * 12 + px + 2) * 10 + c4];
        float logit[25];
#pragma unroll
        for (int k = 0; k < 25; k++) {
            int dy = k / 5, dx = k % 5;
            float4 q = wbox[((py + dy) * 12 + px + dx) * 10 + c4];
            float p = r.x*q.x + r.y*q.y + r.z*q.z + r.w*q.w;
            p += __shfl_xor(p, 1);
            p += __shfl_xor(p, 2);
            p += __shfl_xor(p, 4);
            logit[k] = p;
        }
        float m = logit[0];
#pragma unroll
        for (int k = 1; k < 25; k++) m = fmaxf(m, logit[k]);
        float s = 0.0f;
#pragma unroll
        for (int k = 0; k < 25; k++) { logit[k] = __expf(logit[k] - m); s += logit[k]; }
        float inv_s = 1.0f / s;
#pragma unroll
        for (int t = 0; t < 3; t++) {
            int k = c4 + 8 * t;
            wf[k][g] = logit[k] * inv_s;
        }
        if (c4 == 0) wf[24][g] = logit[24] * inv_s;
        __syncthreads();   // all wbox reads done; smem free for reuse
    }

    // ---- phase B: agg + final ----
    float* dtile = smem;                       // [96][33]
    float* ctile = smem + 96 * 33;             // [96][33]
    for (int li = tid; li < D_ * 96; li += 256) {
        int dd  = li / 96;
        int rem = li - dd * 96;
        int ry  = rem / 12;
        int rx  = rem - ry * 12;
        int yy = yb + ry - 2;
        int xx = x0 + rx - 2;
        bool ok = (yy >= 0) && (yy < H_) && (xx >= 0) && (xx < W_);
        size_t gidx = ((size_t)(b * D_ + dd) * H_ + yy) * W_ + xx;
        AGP(dtile, dd, ry, rx) = ok ? depth[gidx] : 0.0f;
        AGP(ctile, dd, ry, rx) = ok ? cost[gidx]  : 0.0f;
    }
    __syncthreads();

    int p    = tid & 31;
    int px = p & 7, py = p >> 3;
    int dgrp = tid >> 5;
#pragma unroll
    for (int i = 0; i < 4; i++) {
        int d = dgrp * 4 + i;
        float dc = AGP(dtile, d, py + 2, px + 2);

        float wd[25];
        float m1 = -1e30f;
#pragma unroll
        for (int k = 0; k < 25; k++) {
            int dy = k / 5, dx = k % 5;
            float nd = AGP(dtile, d, py + dy, px + dx);
            float l = -fabsf(nd - dc);
            wd[k] = l;
            m1 = fmaxf(m1, l);
        }
        float s1 = 0.0f;
#pragma unroll
        for (int k = 0; k < 25; k++) { wd[k] = __expf(wd[k] - m1); s1 += wd[k]; }
        float inv_s1 = 1.0f / s1;

        float lg[25];
        float m2 = -1e30f;
#pragma unroll
        for (int k = 0; k < 25; k++) {
            float l = (wd[k] * inv_s1) * wf[k][p];
            lg[k] = l;
            m2 = fmaxf(m2, l);
        }
        float s2 = 0.0f;
        float acc = 0.0f;
#pragma unroll
        for (int k = 0; k < 25; k++) {
            float e = __expf(lg[k] - m2);
            s2 += e;
            int dy = k / 5, dx = k % 5;
            acc += AGP(ctile, d, py + dy, px + dx) * e;
        }
        aval[d][p] = acc / s2;
    }
    __syncthreads();

    if (tid < 32) {
        int qx = tid & 7, qy = tid >> 3;
        float m = -1e30f;
#pragma unroll
        for (int dd = 0; dd < D_; dd++) m = fmaxf(m, aval[dd][tid]);
        float s = 0.0f, ws = 0.0f;
#pragma unroll
        for (int dd = 0; dd < D_; dd++) {
            float e = __expf(aval[dd][tid] - m);
            s += e;
            ws += e * AGP(dtile, dd, qy + 2, qx + 2);
        }
        out[(b * H_ + yb + qy) * W_ + x0 + qx] = ws / s;
    }
}

extern "C" void kernel_launch(void* const* d_in, const int* in_sizes, int n_in,
                              void* d_out, int out_size, void* d_ws, size_t ws_size,
                              hipStream_t stream) {
    const float* features = (const float*)d_in[0];  // (3,2,32,128,160)
    const float* intr     = (const float*)d_in[1];  // (3,2,3,3)
    const float* c2w      = (const float*)d_in[2];  // (3,2,4,4)
    const float* depth    = (const float*)d_in[3];  // (2,32,128,160)
    const float* unc      = (const float*)d_in[4];  // (2,128,160)
    float* out = (float*)d_out;

    float*  ws    = (float*)d_ws;
    float*  refT  = ws;                                         // B*HW*C f32
    __half* fh    = (__half*)(refT + (size_t)B_ * HW_ * C_);    // 2*B*HW*C fp16
    float*  cost  = (float*)(fh + (size_t)2 * B_ * HW_ * C_);   // NCOST_
    float*  proj  = cost + NCOST_;                              // 48

    hipLaunchKernelGGL(proj_kernel, dim3(1), dim3(64), 0, stream, intr, c2w, proj);
    hipLaunchKernelGGL(transpose_kernel, dim3(V_ * B_ * H_ * (W_ / 32)), dim3(256), 0, stream,
                       features, refT, fh);
    hipLaunchKernelGGL(cost_kernel, dim3((NPIX_ * 4) / 32), dim3(256), 0, stream,
                       refT, fh, depth, unc, proj, cost);
    hipLaunchKernelGGL(aggfinal_kernel, dim3(NPIX_ / (TX_ * TY_)), dim3(256), 0, stream,
                       refT, depth, cost, out);
}

// Round 15
// 79.156 us; speedup vs baseline: 1.4631x; 1.2480x over previous
//
#include <hip/hip_runtime.h>
#include <hip/hip_fp16.h>
#include <math.h>

#define V_ 3
#define B_ 2
#define C_ 32
#define D_ 32
#define H_ 128
#define W_ 160
#define HW_ (H_*W_)
#define NPIX_ (B_*H_*W_)              // 40960
#define NCOST_ (B_*D_*H_*W_)          // 1310720

struct H8 { __half2 h[4]; };          // 8 fp16 channels (16B)

// ---------------- 4x4 double inverse (adjugate) ----------------
__device__ __forceinline__ void inv4(const double* m, double* o) {
    double inv[16];
    inv[0]  =  m[5]*m[10]*m[15] - m[5]*m[11]*m[14] - m[9]*m[6]*m[15] + m[9]*m[7]*m[14] + m[13]*m[6]*m[11] - m[13]*m[7]*m[10];
    inv[4]  = -m[4]*m[10]*m[15] + m[4]*m[11]*m[14] + m[8]*m[6]*m[15] - m[8]*m[7]*m[14] - m[12]*m[6]*m[11] + m[12]*m[7]*m[10];
    inv[8]  =  m[4]*m[9]*m[15]  - m[4]*m[11]*m[13] - m[8]*m[5]*m[15] + m[8]*m[7]*m[13] + m[12]*m[5]*m[11] - m[12]*m[7]*m[9];
    inv[12] = -m[4]*m[9]*m[14]  + m[4]*m[10]*m[13] + m[8]*m[5]*m[14] - m[8]*m[6]*m[13] - m[12]*m[5]*m[10] + m[12]*m[6]*m[9];
    inv[1]  = -m[1]*m[10]*m[15] + m[1]*m[11]*m[14] + m[9]*m[2]*m[15] - m[9]*m[3]*m[14] - m[13]*m[2]*m[11] + m[13]*m[3]*m[10];
    inv[5]  =  m[0]*m[10]*m[15] - m[0]*m[11]*m[14] - m[8]*m[2]*m[15] + m[8]*m[3]*m[14] + m[12]*m[2]*m[11] - m[12]*m[3]*m[10];
    inv[9]  = -m[0]*m[9]*m[15]  + m[0]*m[11]*m[13] + m[8]*m[1]*m[15] - m[8]*m[3]*m[13] - m[12]*m[1]*m[11] + m[12]*m[3]*m[9];
    inv[13] =  m[0]*m[9]*m[14]  - m[0]*m[10]*m[13] - m[8]*m[1]*m[14] + m[8]*m[2]*m[13] + m[12]*m[1]*m[10] - m[12]*m[2]*m[9];
    inv[2]  =  m[1]*m[6]*m[15]  - m[1]*m[7]*m[14]  - m[5]*m[2]*m[15] + m[5]*m[3]*m[14] + m[13]*m[2]*m[7]  - m[13]*m[3]*m[6];
    inv[6]  = -m[0]*m[6]*m[15]  + m[0]*m[7]*m[14]  + m[4]*m[2]*m[15] - m[4]*m[3]*m[14] - m[12]*m[2]*m[7]  + m[12]*m[3]*m[6];
    inv[10] =  m[0]*m[5]*m[15]  - m[0]*m[7]*m[13]  - m[4]*m[1]*m[15] + m[4]*m[3]*m[13] + m[12]*m[1]*m[7]  - m[12]*m[3]*m[5];
    inv[14] = -m[0]*m[5]*m[14]  + m[0]*m[6]*m[13]  + m[4]*m[1]*m[14] - m[4]*m[2]*m[13] - m[12]*m[1]*m[6]  + m[12]*m[2]*m[5];
    inv[3]  = -m[1]*m[6]*m[11]  + m[1]*m[7]*m[10]  + m[5]*m[2]*m[11] - m[5]*m[3]*m[10] - m[9]*m[2]*m[7]   + m[9]*m[3]*m[6];
    inv[7]  =  m[0]*m[6]*m[11]  - m[0]*m[7]*m[10]  - m[4]*m[2]*m[11] + m[4]*m[3]*m[10] + m[8]*m[2]*m[7]   - m[8]*m[3]*m[6];
    inv[11] = -m[0]*m[5]*m[11]  + m[0]*m[7]*m[9]   + m[4]*m[1]*m[11] - m[4]*m[3]*m[9]  - m[8]*m[1]*m[7]   + m[8]*m[3]*m[5];
    inv[15] =  m[0]*m[5]*m[10]  - m[0]*m[6]*m[9]   - m[4]*m[1]*m[10] + m[4]*m[2]*m[9]  + m[8]*m[1]*m[6]   - m[8]*m[2]*m[5];
    double det = m[0]*inv[0] + m[1]*inv[4] + m[2]*inv[8] + m[3]*inv[12];
    det = 1.0 / det;
    for (int i = 0; i < 16; i++) o[i] = inv[i] * det;
}

__device__ __forceinline__ void mm4(const double* A, const double* Bm, double* Cm) {
    for (int r = 0; r < 4; r++)
        for (int c = 0; c < 4; c++) {
            double s = 0.0;
            for (int k = 0; k < 4; k++) s += A[r*4+k] * Bm[k*4+c];
            Cm[r*4+c] = s;
        }
}

__global__ void proj_kernel(const float* __restrict__ K, const float* __restrict__ c2w,
                            float* __restrict__ proj_out) {
    int t = blockIdx.x * blockDim.x + threadIdx.x;
    if (t >= (V_-1) * B_) return;
    int vv = t / B_;
    int b  = t % B_;
    int v  = vv + 1;
    double sc[16], rc[16];
    for (int i = 0; i < 16; i++) {
        sc[i] = (double)c2w[((size_t)v * B_ + b) * 16 + i];
        rc[i] = (double)c2w[((size_t)0 * B_ + b) * 16 + i];
    }
    double sw[16], rw[16];
    inv4(sc, sw);
    inv4(rc, rw);
    double sK[16], rK[16];
    for (int i = 0; i < 16; i++) { sK[i] = sw[i]; rK[i] = rw[i]; }
    for (int r = 0; r < 3; r++)
        for (int c = 0; c < 3; c++) {
            sK[r*4+c] = (double)K[((size_t)v * B_ + b) * 9 + r*3 + c];
            rK[r*4+c] = (double)K[((size_t)0 * B_ + b) * 9 + r*3 + c];
        }
    double sp[16], rp[16], rpi[16], P[16];
    mm4(sK, sw, sp);
    mm4(rK, rw, rp);
    inv4(rp, rpi);
    mm4(sp, rpi, P);
    float* o = proj_out + (size_t)t * 12;
    for (int r = 0; r < 3; r++)
        for (int c = 0; c < 3; c++) o[r*3+c] = (float)P[r*4+c];
    for (int r = 0; r < 3; r++) o[9+r] = (float)P[r*4+3];
}

// features (V,B,C,H,W) -> refT f32 (B,H,W,C) for view 0, fh fp16 (2,B,H,W,C)
__global__ void __launch_bounds__(256) transpose_kernel(const float* __restrict__ feat,
                                                        float* __restrict__ refT,
                                                        __half* __restrict__ fh) {
    __shared__ float lds[32][33];
    int bid = blockIdx.x;
    int xt = bid % (W_ / 32);
    int y  = (bid / (W_ / 32)) % H_;
    int vb = bid / ((W_ / 32) * H_);
    int v = vb >> 1, b = vb & 1;
    int x0 = xt * 32;
    int tid = threadIdx.x;
    int xl = tid & 31;
    int ch = tid >> 5;
#pragma unroll
    for (int it = 0; it < 4; it++) {
        int c = it * 8 + ch;
        lds[c][xl] = feat[((size_t)(vb * C_ + c) * H_ + y) * W_ + x0 + xl];
    }
    __syncthreads();
    int c4 = tid & 7;
    int xw = tid >> 3;
    float4 o;
    o.x = lds[c4*4+0][xw];
    o.y = lds[c4*4+1][xw];
    o.z = lds[c4*4+2][xw];
    o.w = lds[c4*4+3][xw];
    size_t pix = (size_t)(b * H_ + y) * W_ + x0 + xw;
    if (v == 0) {
        *(float4*)(refT + pix * C_ + c4 * 4) = o;
    } else {
        uint2 st;
        __half2 p0 = __floats2half2_rn(o.x, o.y);
        __half2 p1 = __floats2half2_rn(o.z, o.w);
        st.x = *(unsigned int*)&p0;
        st.y = *(unsigned int*)&p1;
        size_t dst = ((size_t)((v - 1) * B_ + b) * HW_ + (y * W_ + x0 + xw));
        *(uint2*)((unsigned short*)fh + dst * C_ + c4 * 4) = st;
    }
}

// cost (B,D,H,W): block = 32 consecutive pixels x 8 depths (unchanged from R8).
__global__ void __launch_bounds__(256, 4) cost_kernel(const float* __restrict__ refT,
                                                      const __half* __restrict__ fh,
                                                      const float* __restrict__ depth,
                                                      const float* __restrict__ unc,
                                                      const float* __restrict__ proj,
                                                      float* __restrict__ cost) {
    __shared__ float4 lw[2][256];
    __shared__ int4   lo[2][256];
    int tid = threadIdx.x;
    const int blocksPerDt = NPIX_ / 32;           // 1280; grid = 5120
    int dt      = blockIdx.x / blocksPerDt;       // 0..3
    int pixbase = (blockIdx.x % blocksPerDt) * 32;
    int d0 = dt * 8;

    // ---- phase 1: projection per (pixel, d) ----
    {
        int pixl = tid & 31;
        int dl   = tid >> 5;
        int pix = pixbase + pixl;
        int x = pix % W_;
        int y = (pix / W_) % H_;
        int b = pix / HW_;
        float dep = depth[((b * D_ + d0 + dl) * H_ + y) * W_ + x];
        float fx = (float)x, fy = (float)y;
#pragma unroll
        for (int v = 0; v < 2; v++) {
            const float* P = proj + ((size_t)v * B_ + b) * 12;
            float rx = P[0]*fx + P[1]*fy + P[2];
            float ry = P[3]*fx + P[4]*fy + P[5];
            float rz = P[6]*fx + P[7]*fy + P[8];
            float px = rx * dep + P[9];
            float py = ry * dep + P[10];
            float pz = rz * dep + P[11];
            float inv_pz = 1.0f / pz;
            float t0 = px * inv_pz;
            float t1 = py * inv_pz;
            float gx = t0 / ((W_ - 1) * 0.5f) - 1.0f;
            float gy = t1 / ((H_ - 1) * 0.5f) - 1.0f;
            float ix = ((gx + 1.0f) * W_ - 1.0f) * 0.5f;
            float iy = ((gy + 1.0f) * H_ - 1.0f) * 0.5f;
            float x0f = floorf(ix), y0f = floorf(iy);
            float wx = ix - x0f, wy = iy - y0f;
            int x0 = (int)x0f, y0 = (int)y0f;
            int x1 = x0 + 1, y1 = y0 + 1;
            bool vx0 = (x0 >= 0) && (x0 <= W_ - 1);
            bool vx1 = (x1 >= 0) && (x1 <= W_ - 1);
            bool vy0 = (y0 >= 0) && (y0 <= H_ - 1);
            bool vy1 = (y1 >= 0) && (y1 <= H_ - 1);
            float4 w;
            w.x = (vx0 && vy0) ? (1.0f - wx) * (1.0f - wy) : 0.0f;
            w.y = (vx1 && vy0) ? wx * (1.0f - wy) : 0.0f;
            w.z = (vx0 && vy1) ? (1.0f - wx) * wy : 0.0f;
            w.w = (vx1 && vy1) ? wx * wy : 0.0f;
            int xc0 = min(max(x0, 0), W_ - 1), xc1 = min(max(x1, 0), W_ - 1);
            int yc0 = min(max(y0, 0), H_ - 1), yc1 = min(max(y1, 0), H_ - 1);
            int4 o;
            o.x = yc0 * W_ + xc0;
            o.y = yc0 * W_ + xc1;
            o.z = yc1 * W_ + xc0;
            o.w = yc1 * W_ + xc1;
            lw[v][tid] = w;
            lo[v][tid] = o;
        }
    }
    __syncthreads();

    // ---- phase 2: fp16 gathers, 4 lanes per pixel ----
    int c8 = tid & 3;
    int g  = (tid >> 2) & 31;
    int h  = tid >> 7;
    int pix = pixbase + g;
    int x = pix % W_;
    int y = (pix / W_) % H_;
    int b = pix / HW_;

    const float4* rT4 = (const float4*)refT;
    const float4 r0 = rT4[(size_t)pix * 8 + c8 * 2];
    const float4 r1 = rT4[(size_t)pix * 8 + c8 * 2 + 1];
    const H8* fh8 = (const H8*)fh;
    size_t baseA = ((size_t)(0 * B_ + b) * HW_) * 4 + c8;
    size_t baseB = ((size_t)(1 * B_ + b) * HW_) * 4 + c8;

    float u = unc[pix];
    float sig = 1.0f / (1.0f + __expf(-u));

    float myres = 0.0f;
#pragma unroll
    for (int i = 0; i < 4; i++) {
        int e = (h * 4 + i) * 32 + g;
        float pv[2];
#pragma unroll
        for (int v = 0; v < 2; v++) {
            float4 Wt = lw[v][e];
            int4   Of = lo[v][e];
            size_t base = v ? baseB : baseA;
            H8 a  = fh8[base + (size_t)Of.x * 4];
            H8 bq = fh8[base + (size_t)Of.y * 4];
            H8 cq = fh8[base + (size_t)Of.z * 4];
            H8 eq = fh8[base + (size_t)Of.w * 4];
            __half2 w0 = __float2half2_rn(Wt.x);
            __half2 w1 = __float2half2_rn(Wt.y);
            __half2 w2 = __float2half2_rn(Wt.z);
            __half2 w3 = __float2half2_rn(Wt.w);
            __half2 acc0 = __hmul2(w0, a.h[0]);
            __half2 acc1 = __hmul2(w0, a.h[1]);
            __half2 acc2 = __hmul2(w0, a.h[2]);
            __half2 acc3 = __hmul2(w0, a.h[3]);
            acc0 = __hfma2(w1, bq.h[0], acc0);
            acc1 = __hfma2(w1, bq.h[1], acc1);
            acc2 = __hfma2(w1, bq.h[2], acc2);
            acc3 = __hfma2(w1, bq.h[3], acc3);
            acc0 = __hfma2(w2, cq.h[0], acc0);
            acc1 = __hfma2(w2, cq.h[1], acc1);
            acc2 = __hfma2(w2, cq.h[2], acc2);
            acc3 = __hfma2(w2, cq.h[3], acc3);
            acc0 = __hfma2(w3, eq.h[0], acc0);
            acc1 = __hfma2(w3, eq.h[1], acc1);
            acc2 = __hfma2(w3, eq.h[2], acc2);
            acc3 = __hfma2(w3, eq.h[3], acc3);
            float2 f0 = __half22float2(acc0);
            float2 f1 = __half22float2(acc1);
            float2 f2 = __half22float2(acc2);
            float2 f3 = __half22float2(acc3);
            float p = r0.x*f0.x + r0.y*f0.y + r0.z*f1.x + r0.w*f1.y
                    + r1.x*f2.x + r1.y*f2.y + r1.z*f3.x + r1.w*f3.y;
            p += __shfl_xor(p, 1);
            p += __shfl_xor(p, 2);
            pv[v] = p;
        }
        float r = fminf(pv[0], pv[1]) * sig;
        if (c8 == i) myres = r;
    }
    cost[((b * D_ + d0 + h * 4 + c8) * H_ + y) * W_ + x] = myres;
}

// w_feat: block = 32 pixels; 5x36 neighborhood staged in LDS (zero-padded,
// so OOB dots are naturally 0); 8 lanes per pixel; softmax over 25 dots.
__global__ void __launch_bounds__(256) wfeat_kernel(const float* __restrict__ refT,
                                                    float* __restrict__ wfeat) {
    __shared__ float4 wbox[5 * 36 * 8];   // 23 KB
    int tid = threadIdx.x;
    int g  = tid >> 3;
    int c4 = tid & 7;
    int pixbase = blockIdx.x * 32;
    int x0 = pixbase % W_;
    int yb = (pixbase / W_) % H_;
    int b  = pixbase / HW_;
    const float4* rT4 = (const float4*)refT;

    for (int e = tid; e < 5 * 36 * 8; e += 256) {
        int ent = e >> 3, q = e & 7;
        int ry = ent / 36, rx = ent - ry * 36;
        int yy = yb + ry - 2, xx = x0 + rx - 2;
        float4 val = make_float4(0.f, 0.f, 0.f, 0.f);
        if (yy >= 0 && yy < H_ && xx >= 0 && xx < W_)
            val = rT4[(size_t)((b * H_ + yy) * W_ + xx) * 8 + q];
        wbox[e] = val;
    }
    __syncthreads();

    const float4 r = wbox[(2 * 36 + g + 2) * 8 + c4];
    float logit[25];
#pragma unroll
    for (int k = 0; k < 25; k++) {
        int dy = k / 5, dx = k % 5;
        float4 q = wbox[(dy * 36 + g + dx) * 8 + c4];
        float p = r.x*q.x + r.y*q.y + r.z*q.z + r.w*q.w;
        p += __shfl_xor(p, 1);
        p += __shfl_xor(p, 2);
        p += __shfl_xor(p, 4);
        logit[k] = p;
    }
    float m = logit[0];
#pragma unroll
    for (int k = 1; k < 25; k++) m = fmaxf(m, logit[k]);
    float s = 0.0f;
#pragma unroll
    for (int k = 0; k < 25; k++) { logit[k] = __expf(logit[k] - m); s += logit[k]; }
    float inv_s = 1.0f / s;
    int pix = pixbase + g;
#pragma unroll
    for (int t = 0; t < 3; t++) {
        int k = c4 + 8 * t;
        wfeat[(size_t)k * NPIX_ + pix] = logit[k] * inv_s;
    }
    if (c4 == 0) wfeat[(size_t)24 * NPIX_ + pix] = logit[24] * inv_s;
}

// agg: ZERO-LDS direct-gather version. Thread = (x, d); half-wave = 32
// consecutive x -> every tap/wf/cost load is 1-2 contiguous 128B lines,
// L1/L2-resident (per-d slice = 320 KB). Single wd[25] register array
// reused in-place across softmax passes. No barriers; TLP hides latency.
__global__ void __launch_bounds__(256, 4) agg_kernel(const float* __restrict__ depth,
                                                     const float* __restrict__ cost,
                                                     const float* __restrict__ wfeat,
                                                     float* __restrict__ agg) {
    int tid = threadIdx.x;
    int xl = tid & 31;
    int dl = tid >> 5;            // 0..7
    int bid = blockIdx.x;
    int xt  = bid % (W_ / 32);    // 5
    int rem = bid / (W_ / 32);
    int by  = rem % (B_ * H_);    // spatial-minor for L2 halo reuse
    int dg  = rem / (B_ * H_);    // 0..3 (d-group major)
    int y = by % H_;
    int b = by / H_;
    int x = xt * 32 + xl;
    int d = dg * 8 + dl;
    int pix = (b * H_ + y) * W_ + x;
    size_t dslice = (size_t)(b * D_ + d) * HW_;

    float dc = depth[dslice + y * W_ + x];

    float wd[25];
    float m1 = -1e30f;
#pragma unroll
    for (int k = 0; k < 25; k++) {
        int dy = k / 5 - 2, dx = k % 5 - 2;
        int ny = y + dy, nx = x + dx;
        bool ok = (ny >= 0 && ny < H_ && nx >= 0 && nx < W_);
        float nd = ok ? depth[dslice + ny * W_ + nx] : 0.0f;
        float l = -fabsf(nd - dc);
        wd[k] = l;
        m1 = fmaxf(m1, l);
    }
    float s1 = 0.0f;
#pragma unroll
    for (int k = 0; k < 25; k++) { wd[k] = __expf(wd[k] - m1); s1 += wd[k]; }
    float inv_s1 = 1.0f / s1;

    float m2 = -1e30f;
#pragma unroll
    for (int k = 0; k < 25; k++) {
        float l = (wd[k] * inv_s1) * wfeat[(size_t)k * NPIX_ + pix];
        wd[k] = l;
        m2 = fmaxf(m2, l);
    }
    float s2 = 0.0f;
    float acc = 0.0f;
#pragma unroll
    for (int k = 0; k < 25; k++) {
        float e = __expf(wd[k] - m2);
        s2 += e;
        int dy = k / 5 - 2, dx = k % 5 - 2;
        int ny = y + dy, nx = x + dx;
        bool ok = (ny >= 0 && ny < H_ && nx >= 0 && nx < W_);
        float cv = ok ? cost[dslice + ny * W_ + nx] : 0.0f;
        acc += cv * e;
    }
    agg[dslice + y * W_ + x] = acc / s2;
}

// final: per-pixel softmax over D + expectation
__global__ void __launch_bounds__(256) final_kernel(const float* __restrict__ agg,
                                                    const float* __restrict__ depth,
                                                    float* __restrict__ out) {
    int idx = blockIdx.x * 256 + threadIdx.x;
    if (idx >= NPIX_) return;
    int x = idx % W_;
    int y = (idx / W_) % H_;
    int b = idx / (W_ * H_);
    size_t base = ((size_t)(b * D_) * H_ + y) * W_ + x;
    float a[D_];
    float m = -1e30f;
#pragma unroll
    for (int d = 0; d < D_; d++) {
        a[d] = agg[base + (size_t)d * HW_];
        m = fmaxf(m, a[d]);
    }
    float s = 0.0f, ws = 0.0f;
#pragma unroll
    for (int d = 0; d < D_; d++) {
        float e = __expf(a[d] - m);
        s += e;
        ws += e * depth[base + (size_t)d * HW_];
    }
    out[idx] = ws / s;
}

extern "C" void kernel_launch(void* const* d_in, const int* in_sizes, int n_in,
                              void* d_out, int out_size, void* d_ws, size_t ws_size,
                              hipStream_t stream) {
    const float* features = (const float*)d_in[0];  // (3,2,32,128,160)
    const float* intr     = (const float*)d_in[1];  // (3,2,3,3)
    const float* c2w      = (const float*)d_in[2];  // (3,2,4,4)
    const float* depth    = (const float*)d_in[3];  // (2,32,128,160)
    const float* unc      = (const float*)d_in[4];  // (2,128,160)
    float* out = (float*)d_out;

    float*  ws    = (float*)d_ws;
    float*  refT  = ws;                                         // B*HW*C f32
    __half* fh    = (__half*)(refT + (size_t)B_ * HW_ * C_);    // 2*B*HW*C fp16
    float*  cost  = (float*)(fh + (size_t)2 * B_ * HW_ * C_);   // NCOST_
    float*  wfeat = cost + NCOST_;                              // 25*NPIX_
    float*  agg   = wfeat + (size_t)25 * NPIX_;                 // NCOST_
    float*  proj  = agg + NCOST_;                               // 48

    hipLaunchKernelGGL(proj_kernel, dim3(1), dim3(64), 0, stream, intr, c2w, proj);
    hipLaunchKernelGGL(transpose_kernel, dim3(V_ * B_ * H_ * (W_ / 32)), dim3(256), 0, stream,
                       features, refT, fh);
    hipLaunchKernelGGL(cost_kernel, dim3((NPIX_ * 4) / 32), dim3(256), 0, stream,
                       refT, fh, depth, unc, proj, cost);
    hipLaunchKernelGGL(wfeat_kernel, dim3(NPIX_ / 32), dim3(256), 0, stream, refT, wfeat);
    hipLaunchKernelGGL(agg_kernel, dim3((W_ / 32) * B_ * H_ * (D_ / 8)), dim3(256), 0, stream,
                       depth, cost, wfeat, agg);
    hipLaunchKernelGGL(final_kernel, dim3(NPIX_ / 256), dim3(256), 0, stream, agg, depth, out);
}

// Round 16
// 70.015 us; speedup vs baseline: 1.6541x; 1.1306x over previous
//
#include <hip/hip_runtime.h>
#include <hip/hip_fp16.h>
#include <math.h>

#define V_ 3
#define B_ 2
#define C_ 32
#define D_ 32
#define H_ 128
#define W_ 160
#define HW_ (H_*W_)
#define NPIX_ (B_*H_*W_)              // 40960
#define NCOST_ (B_*D_*H_*W_)          // 1310720

struct H8 { __half2 h[4]; };          // 8 fp16 channels (16B)

// ---------------- 4x4 double inverse (adjugate) ----------------
__device__ __forceinline__ void inv4(const double* m, double* o) {
    double inv[16];
    inv[0]  =  m[5]*m[10]*m[15] - m[5]*m[11]*m[14] - m[9]*m[6]*m[15] + m[9]*m[7]*m[14] + m[13]*m[6]*m[11] - m[13]*m[7]*m[10];
    inv[4]  = -m[4]*m[10]*m[15] + m[4]*m[11]*m[14] + m[8]*m[6]*m[15] - m[8]*m[7]*m[14] - m[12]*m[6]*m[11] + m[12]*m[7]*m[10];
    inv[8]  =  m[4]*m[9]*m[15]  - m[4]*m[11]*m[13] - m[8]*m[5]*m[15] + m[8]*m[7]*m[13] + m[12]*m[5]*m[11] - m[12]*m[7]*m[9];
    inv[12] = -m[4]*m[9]*m[14]  + m[4]*m[10]*m[13] + m[8]*m[5]*m[14] - m[8]*m[6]*m[13] - m[12]*m[5]*m[10] + m[12]*m[6]*m[9];
    inv[1]  = -m[1]*m[10]*m[15] + m[1]*m[11]*m[14] + m[9]*m[2]*m[15] - m[9]*m[3]*m[14] - m[13]*m[2]*m[11] + m[13]*m[3]*m[10];
    inv[5]  =  m[0]*m[10]*m[15] - m[0]*m[11]*m[14] - m[8]*m[2]*m[15] + m[8]*m[3]*m[14] + m[12]*m[2]*m[11] - m[12]*m[3]*m[10];
    inv[9]  = -m[0]*m[9]*m[15]  + m[0]*m[11]*m[13] + m[8]*m[1]*m[15] - m[8]*m[3]*m[13] - m[12]*m[1]*m[11] + m[12]*m[3]*m[9];
    inv[13] =  m[0]*m[9]*m[14]  - m[0]*m[10]*m[13] - m[8]*m[1]*m[14] + m[8]*m[2]*m[13] + m[12]*m[1]*m[10] - m[12]*m[2]*m[9];
    inv[2]  =  m[1]*m[6]*m[15]  - m[1]*m[7]*m[14]  - m[5]*m[2]*m[15] + m[5]*m[3]*m[14] + m[13]*m[2]*m[7]  - m[13]*m[3]*m[6];
    inv[6]  = -m[0]*m[6]*m[15]  + m[0]*m[7]*m[14]  + m[4]*m[2]*m[15] - m[4]*m[3]*m[14] - m[12]*m[2]*m[7]  + m[12]*m[3]*m[6];
    inv[10] =  m[0]*m[5]*m[15]  - m[0]*m[7]*m[13]  - m[4]*m[1]*m[15] + m[4]*m[3]*m[13] + m[12]*m[1]*m[7]  - m[12]*m[3]*m[5];
    inv[14] = -m[0]*m[5]*m[14]  + m[0]*m[6]*m[13]  + m[4]*m[1]*m[14] - m[4]*m[2]*m[13] - m[12]*m[1]*m[6]  + m[12]*m[2]*m[5];
    inv[3]  = -m[1]*m[6]*m[11]  + m[1]*m[7]*m[10]  + m[5]*m[2]*m[11] - m[5]*m[3]*m[10] - m[9]*m[2]*m[7]   + m[9]*m[3]*m[6];
    inv[7]  =  m[0]*m[6]*m[11]  - m[0]*m[7]*m[10]  - m[4]*m[2]*m[11] + m[4]*m[3]*m[10] + m[8]*m[2]*m[7]   - m[8]*m[3]*m[6];
    inv[11] = -m[0]*m[5]*m[11]  + m[0]*m[7]*m[9]   + m[4]*m[1]*m[11] - m[4]*m[3]*m[9]  - m[8]*m[1]*m[7]   + m[8]*m[3]*m[5];
    inv[15] =  m[0]*m[5]*m[10]  - m[0]*m[6]*m[9]   - m[4]*m[1]*m[10] + m[4]*m[2]*m[9]  + m[8]*m[1]*m[6]   - m[8]*m[2]*m[5];
    double det = m[0]*inv[0] + m[1]*inv[4] + m[2]*inv[8] + m[3]*inv[12];
    det = 1.0 / det;
    for (int i = 0; i < 16; i++) o[i] = inv[i] * det;
}

__device__ __forceinline__ void mm4(const double* A, const double* Bm, double* Cm) {
    for (int r = 0; r < 4; r++)
        for (int c = 0; c < 4; c++) {
            double s = 0.0;
            for (int k = 0; k < 4; k++) s += A[r*4+k] * Bm[k*4+c];
            Cm[r*4+c] = s;
        }
}

// merged transpose + proj.
// blocks [0, 3840): features (V,B,C,H,W) -> refT f32 (B,H,W,C) view 0,
//                   fh fp16 (2,B,H,W,C) views 1,2.
// block 3840: proj_out (V-1,B,12) (threads 0..3).
__global__ void __launch_bounds__(256) transproj_kernel(const float* __restrict__ feat,
                                                        const float* __restrict__ K,
                                                        const float* __restrict__ c2w,
                                                        float* __restrict__ refT,
                                                        __half* __restrict__ fh,
                                                        float* __restrict__ proj_out) {
    int bid = blockIdx.x;
    int tid = threadIdx.x;
    if (bid == V_ * B_ * H_ * (W_ / 32)) {
        int t = tid;
        if (t >= (V_-1) * B_) return;
        int vv = t / B_;
        int b  = t % B_;
        int v  = vv + 1;
        double sc[16], rc[16];
        for (int i = 0; i < 16; i++) {
            sc[i] = (double)c2w[((size_t)v * B_ + b) * 16 + i];
            rc[i] = (double)c2w[((size_t)0 * B_ + b) * 16 + i];
        }
        double sw[16], rw[16];
        inv4(sc, sw);
        inv4(rc, rw);
        double sK[16], rK[16];
        for (int i = 0; i < 16; i++) { sK[i] = sw[i]; rK[i] = rw[i]; }
        for (int r = 0; r < 3; r++)
            for (int c = 0; c < 3; c++) {
                sK[r*4+c] = (double)K[((size_t)v * B_ + b) * 9 + r*3 + c];
                rK[r*4+c] = (double)K[((size_t)0 * B_ + b) * 9 + r*3 + c];
            }
        double sp[16], rp[16], rpi[16], P[16];
        mm4(sK, sw, sp);
        mm4(rK, rw, rp);
        inv4(rp, rpi);
        mm4(sp, rpi, P);
        float* o = proj_out + (size_t)t * 12;
        for (int r = 0; r < 3; r++)
            for (int c = 0; c < 3; c++) o[r*3+c] = (float)P[r*4+c];
        for (int r = 0; r < 3; r++) o[9+r] = (float)P[r*4+3];
        return;
    }
    __shared__ float lds[32][33];
    int xt = bid % (W_ / 32);
    int y  = (bid / (W_ / 32)) % H_;
    int vb = bid / ((W_ / 32) * H_);
    int v = vb >> 1, b = vb & 1;
    int x0 = xt * 32;
    int xl = tid & 31;
    int ch = tid >> 5;
#pragma unroll
    for (int it = 0; it < 4; it++) {
        int c = it * 8 + ch;
        lds[c][xl] = feat[((size_t)(vb * C_ + c) * H_ + y) * W_ + x0 + xl];
    }
    __syncthreads();
    int c4 = tid & 7;
    int xw = tid >> 3;
    float4 o;
    o.x = lds[c4*4+0][xw];
    o.y = lds[c4*4+1][xw];
    o.z = lds[c4*4+2][xw];
    o.w = lds[c4*4+3][xw];
    size_t pix = (size_t)(b * H_ + y) * W_ + x0 + xw;
    if (v == 0) {
        *(float4*)(refT + pix * C_ + c4 * 4) = o;
    } else {
        uint2 st;
        __half2 p0 = __floats2half2_rn(o.x, o.y);
        __half2 p1 = __floats2half2_rn(o.z, o.w);
        st.x = *(unsigned int*)&p0;
        st.y = *(unsigned int*)&p1;
        size_t dst = ((size_t)((v - 1) * B_ + b) * HW_ + (y * W_ + x0 + xw));
        *(uint2*)((unsigned short*)fh + dst * C_ + c4 * 4) = st;
    }
}

// merged cost + wfeat (independent work, one dispatch so wfeat blocks ride
// in cost's memory-latency shadow).
// blocks [0, 5120): cost (B,D,H,W) — R8 structure.
// blocks [5120, 6400): wfeat (25, NPIX) — R12 structure.
union SmemU {
    struct { float4 lw[2][256]; int4 lo[2][256]; } c;   // 16 KB
    float4 wbox[5 * 36 * 8];                            // 23 KB
};
__global__ void __launch_bounds__(256, 4) costwfeat_kernel(const float* __restrict__ refT,
                                                           const __half* __restrict__ fh,
                                                           const float* __restrict__ depth,
                                                           const float* __restrict__ unc,
                                                           const float* __restrict__ proj,
                                                           float* __restrict__ cost,
                                                           float* __restrict__ wfeat) {
    __shared__ SmemU sm;
    int tid = threadIdx.x;
    int bid = blockIdx.x;
    const int blocksPerDt = NPIX_ / 32;           // 1280; cost grid = 5120

    if (bid < 4 * blocksPerDt) {
        // ================= cost =================
        int dt      = bid / blocksPerDt;
        int pixbase = (bid % blocksPerDt) * 32;
        int d0 = dt * 8;
        {
            int pixl = tid & 31;
            int dl   = tid >> 5;
            int pix = pixbase + pixl;
            int x = pix % W_;
            int y = (pix / W_) % H_;
            int b = pix / HW_;
            float dep = depth[((b * D_ + d0 + dl) * H_ + y) * W_ + x];
            float fx = (float)x, fy = (float)y;
#pragma unroll
            for (int v = 0; v < 2; v++) {
                const float* P = proj + ((size_t)v * B_ + b) * 12;
                float rx = P[0]*fx + P[1]*fy + P[2];
                float ry = P[3]*fx + P[4]*fy + P[5];
                float rz = P[6]*fx + P[7]*fy + P[8];
                float px = rx * dep + P[9];
                float py = ry * dep + P[10];
                float pz = rz * dep + P[11];
                float inv_pz = 1.0f / pz;
                float t0 = px * inv_pz;
                float t1 = py * inv_pz;
                float gx = t0 / ((W_ - 1) * 0.5f) - 1.0f;
                float gy = t1 / ((H_ - 1) * 0.5f) - 1.0f;
                float ix = ((gx + 1.0f) * W_ - 1.0f) * 0.5f;
                float iy = ((gy + 1.0f) * H_ - 1.0f) * 0.5f;
                float x0f = floorf(ix), y0f = floorf(iy);
                float wx = ix - x0f, wy = iy - y0f;
                int x0 = (int)x0f, y0 = (int)y0f;
                int x1 = x0 + 1, y1 = y0 + 1;
                bool vx0 = (x0 >= 0) && (x0 <= W_ - 1);
                bool vx1 = (x1 >= 0) && (x1 <= W_ - 1);
                bool vy0 = (y0 >= 0) && (y0 <= H_ - 1);
                bool vy1 = (y1 >= 0) && (y1 <= H_ - 1);
                float4 w;
                w.x = (vx0 && vy0) ? (1.0f - wx) * (1.0f - wy) : 0.0f;
                w.y = (vx1 && vy0) ? wx * (1.0f - wy) : 0.0f;
                w.z = (vx0 && vy1) ? (1.0f - wx) * wy : 0.0f;
                w.w = (vx1 && vy1) ? wx * wy : 0.0f;
                int xc0 = min(max(x0, 0), W_ - 1), xc1 = min(max(x1, 0), W_ - 1);
                int yc0 = min(max(y0, 0), H_ - 1), yc1 = min(max(y1, 0), H_ - 1);
                int4 o;
                o.x = yc0 * W_ + xc0;
                o.y = yc0 * W_ + xc1;
                o.z = yc1 * W_ + xc0;
                o.w = yc1 * W_ + xc1;
                sm.c.lw[v][tid] = w;
                sm.c.lo[v][tid] = o;
            }
        }
        __syncthreads();

        int c8 = tid & 3;
        int g  = (tid >> 2) & 31;
        int h  = tid >> 7;
        int pix = pixbase + g;
        int x = pix % W_;
        int y = (pix / W_) % H_;
        int b = pix / HW_;

        const float4* rT4 = (const float4*)refT;
        const float4 r0 = rT4[(size_t)pix * 8 + c8 * 2];
        const float4 r1 = rT4[(size_t)pix * 8 + c8 * 2 + 1];
        const H8* fh8 = (const H8*)fh;
        size_t baseA = ((size_t)(0 * B_ + b) * HW_) * 4 + c8;
        size_t baseB = ((size_t)(1 * B_ + b) * HW_) * 4 + c8;

        float u = unc[pix];
        float sig = 1.0f / (1.0f + __expf(-u));

        float myres = 0.0f;
#pragma unroll
        for (int i = 0; i < 4; i++) {
            int e = (h * 4 + i) * 32 + g;
            float pv[2];
#pragma unroll
            for (int v = 0; v < 2; v++) {
                float4 Wt = sm.c.lw[v][e];
                int4   Of = sm.c.lo[v][e];
                size_t base = v ? baseB : baseA;
                H8 a  = fh8[base + (size_t)Of.x * 4];
                H8 bq = fh8[base + (size_t)Of.y * 4];
                H8 cq = fh8[base + (size_t)Of.z * 4];
                H8 eq = fh8[base + (size_t)Of.w * 4];
                __half2 w0 = __float2half2_rn(Wt.x);
                __half2 w1 = __float2half2_rn(Wt.y);
                __half2 w2 = __float2half2_rn(Wt.z);
                __half2 w3 = __float2half2_rn(Wt.w);
                __half2 acc0 = __hmul2(w0, a.h[0]);
                __half2 acc1 = __hmul2(w0, a.h[1]);
                __half2 acc2 = __hmul2(w0, a.h[2]);
                __half2 acc3 = __hmul2(w0, a.h[3]);
                acc0 = __hfma2(w1, bq.h[0], acc0);
                acc1 = __hfma2(w1, bq.h[1], acc1);
                acc2 = __hfma2(w1, bq.h[2], acc2);
                acc3 = __hfma2(w1, bq.h[3], acc3);
                acc0 = __hfma2(w2, cq.h[0], acc0);
                acc1 = __hfma2(w2, cq.h[1], acc1);
                acc2 = __hfma2(w2, cq.h[2], acc2);
                acc3 = __hfma2(w2, cq.h[3], acc3);
                acc0 = __hfma2(w3, eq.h[0], acc0);
                acc1 = __hfma2(w3, eq.h[1], acc1);
                acc2 = __hfma2(w3, eq.h[2], acc2);
                acc3 = __hfma2(w3, eq.h[3], acc3);
                float2 f0 = __half22float2(acc0);
                float2 f1 = __half22float2(acc1);
                float2 f2 = __half22float2(acc2);
                float2 f3 = __half22float2(acc3);
                float p = r0.x*f0.x + r0.y*f0.y + r0.z*f1.x + r0.w*f1.y
                        + r1.x*f2.x + r1.y*f2.y + r1.z*f3.x + r1.w*f3.y;
                p += __shfl_xor(p, 1);
                p += __shfl_xor(p, 2);
                pv[v] = p;
            }
            float r = fminf(pv[0], pv[1]) * sig;
            if (c8 == i) myres = r;
        }
        cost[((b * D_ + d0 + h * 4 + c8) * H_ + y) * W_ + x] = myres;
    } else {
        // ================= wfeat =================
        int wbid = bid - 4 * blocksPerDt;
        int g  = tid >> 3;
        int c4 = tid & 7;
        int pixbase = wbid * 32;
        int x0 = pixbase % W_;
        int yb = (pixbase / W_) % H_;
        int b  = pixbase / HW_;
        const float4* rT4 = (const float4*)refT;

        for (int e = tid; e < 5 * 36 * 8; e += 256) {
            int ent = e >> 3, q = e & 7;
            int ry = ent / 36, rx = ent - ry * 36;
            int yy = yb + ry - 2, xx = x0 + rx - 2;
            float4 val = make_float4(0.f, 0.f, 0.f, 0.f);
            if (yy >= 0 && yy < H_ && xx >= 0 && xx < W_)
                val = rT4[(size_t)((b * H_ + yy) * W_ + xx) * 8 + q];
            sm.wbox[e] = val;
        }
        __syncthreads();

        const float4 r = sm.wbox[(2 * 36 + g + 2) * 8 + c4];
        float logit[25];
#pragma unroll
        for (int k = 0; k < 25; k++) {
            int dy = k / 5, dx = k % 5;
            float4 q = sm.wbox[(dy * 36 + g + dx) * 8 + c4];
            float p = r.x*q.x + r.y*q.y + r.z*q.z + r.w*q.w;
            p += __shfl_xor(p, 1);
            p += __shfl_xor(p, 2);
            p += __shfl_xor(p, 4);
            logit[k] = p;
        }
        float m = logit[0];
#pragma unroll
        for (int k = 1; k < 25; k++) m = fmaxf(m, logit[k]);
        float s = 0.0f;
#pragma unroll
        for (int k = 0; k < 25; k++) { logit[k] = __expf(logit[k] - m); s += logit[k]; }
        float inv_s = 1.0f / s;
        int pix = pixbase + g;
#pragma unroll
        for (int t = 0; t < 3; t++) {
            int k = c4 + 8 * t;
            wfeat[(size_t)k * NPIX_ + pix] = logit[k] * inv_s;
        }
        if (c4 == 0) wfeat[(size_t)24 * NPIX_ + pix] = logit[24] * inv_s;
    }
}

// fused agg + final: block = one row-aligned run of 32 pixels, ALL 32 d.
// Thread (xl, dl) computes 4 depths (d = dl*4+i) with R14's zero-LDS direct
// gathers (coalesced, L2-resident); wf staged once per block; aval/dval in
// small LDS; per-pixel softmax over D at the end. No agg round trip.
// Inner softmaxes: m1 == 0 analytically; 2nd-softmax logits in [0,1].
__global__ void __launch_bounds__(256, 4) aggfinal_kernel(const float* __restrict__ depth,
                                                          const float* __restrict__ cost,
                                                          const float* __restrict__ wfeat,
                                                          float* __restrict__ out) {
    __shared__ float wf[25][33];
    __shared__ float aval[D_][33];
    __shared__ float dval[D_][33];
    int tid = threadIdx.x;
    int xl = tid & 31;
    int dl = tid >> 5;            // 0..7
    int bid = blockIdx.x;
    int xt = bid % (W_ / 32);
    int by = bid / (W_ / 32);
    int y = by % H_;
    int b = by / H_;
    int x = xt * 32 + xl;
    int pix = (b * H_ + y) * W_ + x;

    for (int li = tid; li < 25 * 32; li += 256) {
        int k  = li >> 5;
        int pp = li & 31;
        wf[k][pp] = wfeat[(size_t)k * NPIX_ + (b * H_ + y) * W_ + xt * 32 + pp];
    }
    __syncthreads();

#pragma unroll
    for (int i = 0; i < 4; i++) {
        int d = dl * 4 + i;
        size_t dslice = (size_t)(b * D_ + d) * HW_;
        float dc = depth[dslice + y * W_ + x];

        float wd[25];
        float s1 = 0.0f;
#pragma unroll
        for (int k = 0; k < 25; k++) {
            int dy = k / 5 - 2, dx = k % 5 - 2;
            int ny = y + dy, nx = x + dx;
            bool ok = (ny >= 0 && ny < H_ && nx >= 0 && nx < W_);
            float nd = ok ? depth[dslice + ny * W_ + nx] : 0.0f;
            float e = __expf(-fabsf(nd - dc));   // m1 == 0 analytically
            wd[k] = e;
            s1 += e;
        }
        float inv_s1 = 1.0f / s1;

        float s2 = 0.0f;
        float acc = 0.0f;
#pragma unroll
        for (int k = 0; k < 25; k++) {
            float e = __expf((wd[k] * inv_s1) * wf[k][xl]);  // logits in [0,1]
            s2 += e;
            int dy = k / 5 - 2, dx = k % 5 - 2;
            int ny = y + dy, nx = x + dx;
            bool ok = (ny >= 0 && ny < H_ && nx >= 0 && nx < W_);
            float cv = ok ? cost[dslice + ny * W_ + nx] : 0.0f;
            acc += cv * e;
        }
        aval[d][xl] = acc / s2;
        dval[d][xl] = dc;
    }
    __syncthreads();

    if (tid < 32) {
        float m = -1e30f;
#pragma unroll
        for (int dd = 0; dd < D_; dd++) m = fmaxf(m, aval[dd][tid]);
        float s = 0.0f, ws = 0.0f;
#pragma unroll
        for (int dd = 0; dd < D_; dd++) {
            float e = __expf(aval[dd][tid] - m);
            s += e;
            ws += e * dval[dd][tid];
        }
        out[(b * H_ + y) * W_ + xt * 32 + tid] = ws / s;
    }
}

extern "C" void kernel_launch(void* const* d_in, const int* in_sizes, int n_in,
                              void* d_out, int out_size, void* d_ws, size_t ws_size,
                              hipStream_t stream) {
    const float* features = (const float*)d_in[0];  // (3,2,32,128,160)
    const float* intr     = (const float*)d_in[1];  // (3,2,3,3)
    const float* c2w      = (const float*)d_in[2];  // (3,2,4,4)
    const float* depth    = (const float*)d_in[3];  // (2,32,128,160)
    const float* unc      = (const float*)d_in[4];  // (2,128,160)
    float* out = (float*)d_out;

    float*  ws    = (float*)d_ws;
    float*  refT  = ws;                                         // B*HW*C f32
    __half* fh    = (__half*)(refT + (size_t)B_ * HW_ * C_);    // 2*B*HW*C fp16
    float*  cost  = (float*)(fh + (size_t)2 * B_ * HW_ * C_);   // NCOST_
    float*  wfeat = cost + NCOST_;                              // 25*NPIX_
    float*  proj  = wfeat + (size_t)25 * NPIX_;                 // 48

    hipLaunchKernelGGL(transproj_kernel, dim3(V_ * B_ * H_ * (W_ / 32) + 1), dim3(256), 0, stream,
                       features, intr, c2w, refT, fh, proj);
    hipLaunchKernelGGL(costwfeat_kernel, dim3((NPIX_ * 4) / 32 + NPIX_ / 32), dim3(256), 0, stream,
                       refT, fh, depth, unc, proj, cost, wfeat);
    hipLaunchKernelGGL(aggfinal_kernel, dim3(NPIX_ / 32), dim3(256), 0, stream,
                       depth, cost, wfeat, out);
}